// Round 14
// baseline (374.127 us; speedup 1.0000x reference)
//
#include <hip/hip_runtime.h>

#define NU 100000
#define NI 200000
#define NN 300000
#define NNZE 1200000
#define D 64
#define OS 256   // (L+1)*D output row stride
#define TPB 4    // tiles (of 64 rows) per block in k_fused

typedef __attribute__((ext_vector_type(8))) short s16x8;
typedef __attribute__((ext_vector_type(4))) float f32x4;

__device__ __forceinline__ float bf2f(unsigned short u) {
    return __uint_as_float(((unsigned int)u) << 16);
}
__device__ __forceinline__ unsigned short f2bf(float f) {
    unsigned int u = __float_as_uint(f);
    u = (u + 0x7FFF + ((u >> 16) & 1)) >> 16;   // RNE
    return (unsigned short)u;
}

// ---------------- concat -> out chunk0 (fp32, nt) + ebf (bf16 activation) ----
__global__ void k_concat(const float* __restrict__ ue, const float* __restrict__ ie,
                         float* __restrict__ out, unsigned short* __restrict__ ebf) {
    int idx = blockIdx.x * blockDim.x + threadIdx.x;
    if (idx >= NN * 16) return;
    int n = idx >> 4, c = idx & 15;
    float4 v;
    if (n < NU) v = ((const float4*)(ue + (size_t)n * D))[c];
    else        v = ((const float4*)(ie + (size_t)(n - NU) * D))[c];
    f32x4 vv = {v.x, v.y, v.z, v.w};
    __builtin_nontemporal_store(vv, (f32x4*)(out + (size_t)n * OS) + c);
    ushort4 b;
    b.x = f2bf(v.x); b.y = f2bf(v.y); b.z = f2bf(v.z); b.w = f2bf(v.w);
    *(ushort4*)(ebf + (size_t)n * D + c * 4) = b;
}

// ---------------- CSR build ----------------
__global__ void k_hist(const int* __restrict__ rows, int* __restrict__ cnt) {
    int e = blockIdx.x * blockDim.x + threadIdx.x;
    if (e < NNZE) atomicAdd(&cnt[rows[e]], 1);
}

__global__ void k_scan1(const int* __restrict__ cnt, int* __restrict__ rowptr,
                        int* __restrict__ bsum) {
    __shared__ int s[1024];
    int t = threadIdx.x, g = blockIdx.x * 1024 + t;
    int x = (g < NN) ? cnt[g] : 0;
    s[t] = x;
    __syncthreads();
    for (int off = 1; off < 1024; off <<= 1) {
        int y = (t >= off) ? s[t - off] : 0;
        __syncthreads();
        s[t] += y;
        __syncthreads();
    }
    if (g < NN) rowptr[g + 1] = s[t];
    if (t == 1023) bsum[blockIdx.x] = s[1023];
}

__global__ void k_scan2(int* __restrict__ bsum, int nb) {
    __shared__ int s[512];
    int t = threadIdx.x;
    int x = (t < nb) ? bsum[t] : 0;
    s[t] = x;
    __syncthreads();
    for (int off = 1; off < 512; off <<= 1) {
        int y = (t >= off) ? s[t - off] : 0;
        __syncthreads();
        s[t] += y;
        __syncthreads();
    }
    if (t < nb) bsum[t] = s[t];
}

__global__ void k_scan3(int* __restrict__ rowptr, const int* __restrict__ bsum,
                        int* __restrict__ cur) {
    int t = threadIdx.x, g = blockIdx.x * 1024 + t;
    if (g < NN) {
        int off = (blockIdx.x > 0) ? bsum[blockIdx.x - 1] : 0;
        int v = rowptr[g + 1] + off;
        rowptr[g + 1] = v;
        if (g + 1 < NN) cur[g + 1] = v;
    }
    if (g == 0) { rowptr[0] = 0; cur[0] = 0; }
}

__global__ void k_scatter(const int* __restrict__ rows, const int* __restrict__ cols,
                          const float* __restrict__ vals, int* __restrict__ cur,
                          long long* __restrict__ ecv) {
    int e = blockIdx.x * blockDim.x + threadIdx.x;
    if (e >= NNZE) return;
    int r = rows[e];
    int pos = atomicAdd(&cur[r], 1);
    unsigned long long packed = (unsigned int)cols[e]
        | ((unsigned long long)(unsigned int)__float_as_int(vals[e]) << 32);
    ecv[pos] = (long long)packed;
}

// ---------------- fused layer: SpMM (combined-row gather) + MFMA dense -------
// 4 tiles of 64 rows per block; W staged once. Per tile: 16-lane group handles
// 4 CONTIGUOUS rows' edges in ONE 8-deep loop (boundary-select accumulate).
__global__ __launch_bounds__(256) void k_fused(
    const int* __restrict__ rowptr, const long long* __restrict__ ecv,
    const unsigned short* __restrict__ ebf_in, unsigned short* __restrict__ ebf_out,
    const float* __restrict__ Wc, const float* __restrict__ bc,
    const float* __restrict__ We, const float* __restrict__ be,
    float* __restrict__ outN) {
    __shared__ unsigned short sWT[2][64 * 64];  // W^T [n][k] bf16, XOR-swizzled
    __shared__ unsigned short sS[64 * 64];      // side tile [row][k] bf16, swizzled

    int tid = threadIdx.x;

    // stage both W matrices transposed->bf16 into LDS (once)
    #pragma unroll
    for (int m = 0; m < 2; m++) {
        const float* W = m ? We : Wc;
        int base = tid * 16;
        int k = base >> 6, n = base & 63;
        #pragma unroll
        for (int i = 0; i < 4; i++) {
            float4 v = *(const float4*)(W + k * 64 + n + i * 4);
            #pragma unroll
            for (int j = 0; j < 4; j++) {
                int col = n + i * 4 + j;
                int byteoff = (col * 128 + k * 2) ^ ((col & 7) << 4);
                float fv = (j == 0) ? v.x : (j == 1) ? v.y : (j == 2) ? v.z : v.w;
                *(unsigned short*)((char*)&sWT[m][0] + byteoff) = f2bf(fv);
            }
        }
    }

    int wid = tid >> 6, lane64 = tid & 63;
    int lg = lane64 >> 4, lr = lane64 & 15;
    int grp = tid >> 4, lane = tid & 15;

    // per-layer bias (same all tiles)
    float bj[4];
    #pragma unroll
    for (int c = 0; c < 4; c++) bj[c] = bc[c * 16 + lr] + be[c * 16 + lr];

    for (int t = 0; t < TPB; t++) {
        int n0 = (blockIdx.x * TPB + t) * 64;

        // issue elementwise-operand loads early (overlap gather phase)
        int rowA = n0 + wid * 16 + lr;
        int rowAc = rowA < NN ? rowA : NN - 1;
        size_t abase = (size_t)rowAc * D;
        s16x8 ef0 = *(const s16x8*)(ebf_in + abase + lg * 8);
        s16x8 ef1 = *(const s16x8*)(ebf_in + abase + 32 + lg * 8);

        // ---- SpMM: 4 contiguous rows per 16-lane group, one combined loop ----
        {
            int R0 = n0 + grp * 4;
            int rp0, rp1, rp2, rp3, rp4;
            {
                int r0 = R0 < NN ? R0 : NN;
                int r1 = R0 + 1 < NN ? R0 + 1 : NN;
                int r2 = R0 + 2 < NN ? R0 + 2 : NN;
                int r3 = R0 + 3 < NN ? R0 + 3 : NN;
                int r4 = R0 + 4 < NN ? R0 + 4 : NN;
                rp0 = rowptr[r0]; rp1 = rowptr[r1]; rp2 = rowptr[r2];
                rp3 = rowptr[r3]; rp4 = rowptr[r4];
            }
            float a[4][4];
            #pragma unroll
            for (int rr = 0; rr < 4; rr++)
                #pragma unroll
                for (int cc = 0; cc < 4; cc++) a[rr][cc] = 0.f;

            for (int i = rp0; i < rp4; i += 8) {
                unsigned long long e[8];
                #pragma unroll
                for (int k = 0; k < 8; k++)
                    e[k] = (i + k < rp4) ? (unsigned long long)ecv[i + k] : 0ull;
                ushort4 gg[8];
                float v[8];
                #pragma unroll
                for (int k = 0; k < 8; k++) {
                    int c = (int)(e[k] & 0xFFFFFFFFu);
                    v[k] = __int_as_float((int)(e[k] >> 32));
                    gg[k] = *(const ushort4*)(ebf_in + (size_t)c * D + lane * 4);
                }
                #pragma unroll
                for (int k = 0; k < 8; k++) {
                    int idx = i + k;
                    float gx = bf2f(gg[k].x), gy = bf2f(gg[k].y);
                    float gz = bf2f(gg[k].z), gw = bf2f(gg[k].w);
                    float w0 = (idx < rp1) ? v[k] : 0.f;
                    float w1 = (idx >= rp1 && idx < rp2) ? v[k] : 0.f;
                    float w2 = (idx >= rp2 && idx < rp3) ? v[k] : 0.f;
                    float w3 = (idx >= rp3) ? v[k] : 0.f;
                    a[0][0] += w0 * gx; a[0][1] += w0 * gy; a[0][2] += w0 * gz; a[0][3] += w0 * gw;
                    a[1][0] += w1 * gx; a[1][1] += w1 * gy; a[1][2] += w1 * gz; a[1][3] += w1 * gw;
                    a[2][0] += w2 * gx; a[2][1] += w2 * gy; a[2][2] += w2 * gz; a[2][3] += w2 * gw;
                    a[3][0] += w3 * gx; a[3][1] += w3 * gy; a[3][2] += w3 * gz; a[3][3] += w3 * gw;
                }
            }
            #pragma unroll
            for (int rr = 0; rr < 4; rr++) {
                int lrow = grp * 4 + rr;
                ushort4 r;
                r.x = f2bf(a[rr][0]); r.y = f2bf(a[rr][1]);
                r.z = f2bf(a[rr][2]); r.w = f2bf(a[rr][3]);
                int byteoff = (lrow * 128 + lane * 8) ^ ((lrow & 7) << 4);
                *(ushort4*)((char*)&sS[0] + byteoff) = r;
            }
        }

        __syncthreads();   // A: sS ready (t=0 also covers sWT)

        // A-fragments from LDS side tile
        int lrowA = wid * 16 + lr;
        s16x8 sf[2], wf[2];
        s16x8 ef[2] = {ef0, ef1};
        #pragma unroll
        for (int kb = 0; kb < 2; kb++) {
            int byteoff = (lrowA * 128 + (kb * 32 + lg * 8) * 2) ^ ((lrowA & 7) << 4);
            sf[kb] = *(const s16x8*)((const char*)&sS[0] + byteoff);
            #pragma unroll
            for (int j = 0; j < 8; j++) {
                float p = bf2f((unsigned short)sf[kb][j]) * bf2f((unsigned short)ef[kb][j]);
                wf[kb][j] = (short)f2bf(p);
            }
        }

        __syncthreads();   // B: sS consumed; next tile may overwrite

        f32x4 acc[4];
        #pragma unroll
        for (int c = 0; c < 4; c++) acc[c] = (f32x4){bj[c], bj[c], bj[c], bj[c]};

        #pragma unroll
        for (int c = 0; c < 4; c++) {
            #pragma unroll
            for (int kb = 0; kb < 2; kb++) {
                int row = c * 16 + lr;
                int byteoff = (row * 128 + (kb * 32 + lg * 8) * 2) ^ ((row & 7) << 4);
                s16x8 bWc = *(const s16x8*)((const char*)&sWT[0][0] + byteoff);
                s16x8 bWe = *(const s16x8*)((const char*)&sWT[1][0] + byteoff);
                acc[c] = __builtin_amdgcn_mfma_f32_16x16x32_bf16(sf[kb], bWc, acc[c], 0, 0, 0);
                acc[c] = __builtin_amdgcn_mfma_f32_16x16x32_bf16(wf[kb], bWe, acc[c], 0, 0, 0);
            }
        }

        float o[4][4];
        float ssq[4] = {0.f, 0.f, 0.f, 0.f};
        #pragma unroll
        for (int c = 0; c < 4; c++) {
            #pragma unroll
            for (int r = 0; r < 4; r++) {
                float x = acc[c][r];
                float y = (x > 0.f) ? x : 0.2f * x;
                o[c][r] = y;
                ssq[r] += y * y;
            }
        }
        #pragma unroll
        for (int r = 0; r < 4; r++) {
            ssq[r] += __shfl_xor(ssq[r], 1);
            ssq[r] += __shfl_xor(ssq[r], 2);
            ssq[r] += __shfl_xor(ssq[r], 4);
            ssq[r] += __shfl_xor(ssq[r], 8);
        }
        #pragma unroll
        for (int r = 0; r < 4; r++) {
            int row = n0 + wid * 16 + lg * 4 + r;
            if (row < NN) {
                float sc = 1.0f / fmaxf(sqrtf(ssq[r]), 1e-12f);
                #pragma unroll
                for (int c = 0; c < 4; c++) {
                    __builtin_nontemporal_store(o[c][r] * sc,
                                                &outN[(size_t)row * OS + c * 16 + lr]);
                    ebf_out[(size_t)row * D + c * 16 + lr] = f2bf(o[c][r]);
                }
            }
        }
    }
}

extern "C" void kernel_launch(void* const* d_in, const int* in_sizes, int n_in,
                              void* d_out, int out_size, void* d_ws, size_t ws_size,
                              hipStream_t stream) {
    const int*   rows = (const int*)d_in[0];
    const int*   cols = (const int*)d_in[1];
    const float* vals = (const float*)d_in[2];
    const float* ue   = (const float*)d_in[3];
    const float* ie   = (const float*)d_in[4];
    const float* Wc   = (const float*)d_in[5];
    const float* bc   = (const float*)d_in[6];
    const float* We   = (const float*)d_in[7];
    const float* be   = (const float*)d_in[8];
    float* out = (float*)d_out;

    // ws layout (~87 MB): double-buffered ebf + CSR.
    unsigned short* eb0 = (unsigned short*)d_ws;            // NN*D bf16 (38.4MB)
    unsigned short* eb1 = eb0 + (size_t)NN * D;             // NN*D bf16 (38.4MB)
    int*   cnt    = (int*)d_ws;                             // NN (build only)
    int*   cur    = cnt + NN;                               // NN (build only)
    int*   rowptr = (int*)(eb1 + (size_t)NN * D);           // NN+1
    int*   bsum   = rowptr + NN + 1;                        // 512
    long long* ecv = (long long*)(bsum + 512);              // NNZE (9.6MB)

    const int NB_SCAN = (NN + 1023) / 1024;  // 293

    // ---- build CSR ----
    hipMemsetAsync(cnt, 0, (size_t)NN * sizeof(int), stream);
    k_hist<<<(NNZE + 255) / 256, 256, 0, stream>>>(rows, cnt);
    k_scan1<<<NB_SCAN, 1024, 0, stream>>>(cnt, rowptr, bsum);
    k_scan2<<<1, 512, 0, stream>>>(bsum, NB_SCAN);
    k_scan3<<<NB_SCAN, 1024, 0, stream>>>(rowptr, bsum, cur);
    k_scatter<<<(NNZE + 255) / 256, 256, 0, stream>>>(rows, cols, vals, cur, ecv);

    // ---- embeddings (also initializes eb0; must follow scatter) ----
    k_concat<<<(NN * 16 + 255) / 256, 256, 0, stream>>>(ue, ie, out, eb0);

    const int NTILES = (NN + 63) / 64;                 // 4688
    const int GB_FUSED = (NTILES + TPB - 1) / TPB;     // 1172
    unsigned short* eb[2] = {eb0, eb1};
    for (int l = 0; l < 3; l++) {
        k_fused<<<GB_FUSED, 256, 0, stream>>>(
            rowptr, ecv, eb[l & 1], eb[(l + 1) & 1],
            Wc + l * 4096, bc + l * 64,
            We + l * 4096, be + l * 64, out + (l + 1) * 64);
    }
}

// Round 15
// 333.575 us; speedup vs baseline: 1.1216x; 1.1216x over previous
//
#include <hip/hip_runtime.h>

#define NU 100000
#define NI 200000
#define NN 300000
#define NNZE 1200000
#define D 64
#define OS 256   // (L+1)*D output row stride

typedef __attribute__((ext_vector_type(8))) short s16x8;
typedef __attribute__((ext_vector_type(4))) float f32x4;

__device__ __forceinline__ float bf2f(unsigned short u) {
    return __uint_as_float(((unsigned int)u) << 16);
}
__device__ __forceinline__ unsigned short f2bf(float f) {
    unsigned int u = __float_as_uint(f);
    u = (u + 0x7FFF + ((u >> 16) & 1)) >> 16;   // RNE
    return (unsigned short)u;
}

// ---------------- pre-transpose W -> swizzled bf16 images (once) -------------
// blockIdx.x = l*2+m. Output layout identical to the k_fused LDS image.
__global__ void k_prepw(const float* __restrict__ Wc, const float* __restrict__ We,
                        unsigned short* __restrict__ wbf) {
    int lm = blockIdx.x;                 // 0..5
    int l = lm >> 1, m = lm & 1;
    const float* W = (m ? We : Wc) + l * 4096;
    unsigned short* dst = wbf + lm * 4096;
    int tid = threadIdx.x;
    int base = tid * 16;
    int k = base >> 6, n = base & 63;
    #pragma unroll
    for (int i = 0; i < 4; i++) {
        float4 v = *(const float4*)(W + k * 64 + n + i * 4);
        #pragma unroll
        for (int j = 0; j < 4; j++) {
            int col = n + i * 4 + j;
            int byteoff = (col * 128 + k * 2) ^ ((col & 7) << 4);
            float fv = (j == 0) ? v.x : (j == 1) ? v.y : (j == 2) ? v.z : v.w;
            *(unsigned short*)((char*)dst + byteoff) = f2bf(fv);
        }
    }
}

// ------- concat -> out chunk0 (fp32, nt) + ebf (bf16) + fused edge hist ------
__global__ void k_concat(const float* __restrict__ ue, const float* __restrict__ ie,
                         float* __restrict__ out, unsigned short* __restrict__ ebf,
                         const int* __restrict__ rows, int* __restrict__ cnt) {
    int idx = blockIdx.x * blockDim.x + threadIdx.x;
    if (idx < NNZE) atomicAdd(&cnt[rows[idx]], 1);   // hist hides under concat
    if (idx >= NN * 16) return;
    int n = idx >> 4, c = idx & 15;
    float4 v;
    if (n < NU) v = ((const float4*)(ue + (size_t)n * D))[c];
    else        v = ((const float4*)(ie + (size_t)(n - NU) * D))[c];
    f32x4 vv = {v.x, v.y, v.z, v.w};
    __builtin_nontemporal_store(vv, (f32x4*)(out + (size_t)n * OS) + c);
    ushort4 b;
    b.x = f2bf(v.x); b.y = f2bf(v.y); b.z = f2bf(v.z); b.w = f2bf(v.w);
    *(ushort4*)(ebf + (size_t)n * D + c * 4) = b;
}

// ---------------- CSR build ----------------
__global__ void k_scan1(const int* __restrict__ cnt, int* __restrict__ rowptr,
                        int* __restrict__ bsum) {
    __shared__ int s[1024];
    int t = threadIdx.x, g = blockIdx.x * 1024 + t;
    int x = (g < NN) ? cnt[g] : 0;
    s[t] = x;
    __syncthreads();
    for (int off = 1; off < 1024; off <<= 1) {
        int y = (t >= off) ? s[t - off] : 0;
        __syncthreads();
        s[t] += y;
        __syncthreads();
    }
    if (g < NN) rowptr[g + 1] = s[t];
    if (t == 1023) bsum[blockIdx.x] = s[1023];
}

__global__ void k_scan2(int* __restrict__ bsum, int nb) {
    __shared__ int s[512];
    int t = threadIdx.x;
    int x = (t < nb) ? bsum[t] : 0;
    s[t] = x;
    __syncthreads();
    for (int off = 1; off < 512; off <<= 1) {
        int y = (t >= off) ? s[t - off] : 0;
        __syncthreads();
        s[t] += y;
        __syncthreads();
    }
    if (t < nb) bsum[t] = s[t];
}

__global__ void k_scan3(int* __restrict__ rowptr, const int* __restrict__ bsum,
                        int* __restrict__ cur) {
    int t = threadIdx.x, g = blockIdx.x * 1024 + t;
    if (g < NN) {
        int off = (blockIdx.x > 0) ? bsum[blockIdx.x - 1] : 0;
        int v = rowptr[g + 1] + off;
        rowptr[g + 1] = v;
        if (g + 1 < NN) cur[g + 1] = v;
    }
    if (g == 0) { rowptr[0] = 0; cur[0] = 0; }
}

__global__ void k_scatter(const int* __restrict__ rows, const int* __restrict__ cols,
                          const float* __restrict__ vals, int* __restrict__ cur,
                          long long* __restrict__ ecv) {
    int e = blockIdx.x * blockDim.x + threadIdx.x;
    if (e >= NNZE) return;
    int r = rows[e];
    int pos = atomicAdd(&cur[r], 1);
    unsigned long long packed = (unsigned int)cols[e]
        | ((unsigned long long)(unsigned int)__float_as_int(vals[e]) << 32);
    ecv[pos] = (long long)packed;
}

// ---------------- fused layer: SpMM (gather, LDS) + MFMA dense ---------------
// Round-13 structure; W staged by plain vector copy from precomputed image.
__global__ __launch_bounds__(256) void k_fused(
    const int* __restrict__ rowptr, const long long* __restrict__ ecv,
    const unsigned short* __restrict__ ebf_in, unsigned short* __restrict__ ebf_out,
    const unsigned short* __restrict__ wsrc,   // this layer's 16KB swizzled W^T
    const float* __restrict__ bc, const float* __restrict__ be,
    float* __restrict__ outN) {
    __shared__ unsigned short sWT[2][64 * 64];  // W^T [n][k] bf16, XOR-swizzled
    __shared__ unsigned short sS[64 * 64];      // side tile [row][k] bf16, swizzled

    int tid = threadIdx.x;
    int n0 = blockIdx.x * 64;

    // stage W: linear 16KB vector copy (swizzle baked into the image)
    {
        unsigned short* dst = &sWT[0][0];
        #pragma unroll
        for (int i = 0; i < 4; i++) {
            int idx = i * 2048 + tid * 8;
            *(s16x8*)(dst + idx) = *(const s16x8*)(wsrc + idx);
        }
    }

    // SpMM phase: group = tid>>4 handles rows n0+group*4 .. +3
    {
        int grp = tid >> 4, lane = tid & 15;
        #pragma unroll
        for (int rr = 0; rr < 4; rr++) {
            int lrow = grp * 4 + rr;
            int row = n0 + lrow;
            float a0 = 0.f, a1 = 0.f, a2 = 0.f, a3 = 0.f;
            if (row < NN) {
                int beg = rowptr[row], end = rowptr[row + 1];
                for (int i = beg; i < end; i += 8) {
                    unsigned long long e[8];
                    e[0] = (unsigned long long)ecv[i];
                    #pragma unroll
                    for (int k = 1; k < 8; k++)
                        e[k] = (i + k < end) ? (unsigned long long)ecv[i + k] : 0ull;
                    ushort4 gg[8];
                    float v[8];
                    #pragma unroll
                    for (int k = 0; k < 8; k++) {
                        int c = (int)(e[k] & 0xFFFFFFFFu);
                        v[k] = __int_as_float((int)(e[k] >> 32));
                        gg[k] = *(const ushort4*)(ebf_in + (size_t)c * D + lane * 4);
                    }
                    #pragma unroll
                    for (int k = 0; k < 8; k++) {
                        a0 += v[k] * bf2f(gg[k].x);
                        a1 += v[k] * bf2f(gg[k].y);
                        a2 += v[k] * bf2f(gg[k].z);
                        a3 += v[k] * bf2f(gg[k].w);
                    }
                }
            }
            ushort4 r;
            r.x = f2bf(a0); r.y = f2bf(a1); r.z = f2bf(a2); r.w = f2bf(a3);
            int byteoff = (lrow * 128 + lane * 8) ^ ((lrow & 7) << 4);
            *(ushort4*)((char*)&sS[0] + byteoff) = r;
        }
    }

    int wid = tid >> 6, lane = tid & 63;
    int lg = lane >> 4, lr = lane & 15;

    int rowA = n0 + wid * 16 + lr;
    int rowAc = rowA < NN ? rowA : NN - 1;
    size_t abase = (size_t)rowAc * D;
    s16x8 ef[2];
    ef[0] = *(const s16x8*)(ebf_in + abase + lg * 8);
    ef[1] = *(const s16x8*)(ebf_in + abase + 32 + lg * 8);

    f32x4 acc[4];
    #pragma unroll
    for (int c = 0; c < 4; c++) {
        float bj = bc[c * 16 + lr] + be[c * 16 + lr];
        acc[c] = (f32x4){bj, bj, bj, bj};
    }

    __syncthreads();

    // A-fragments from the LDS side tile (swizzled, 2-way conflict max)
    int lrowA = wid * 16 + lr;
    s16x8 sf[2], wf[2];
    #pragma unroll
    for (int kb = 0; kb < 2; kb++) {
        int byteoff = (lrowA * 128 + (kb * 32 + lg * 8) * 2) ^ ((lrowA & 7) << 4);
        sf[kb] = *(const s16x8*)((const char*)&sS[0] + byteoff);
        #pragma unroll
        for (int j = 0; j < 8; j++) {
            float p = bf2f((unsigned short)sf[kb][j]) * bf2f((unsigned short)ef[kb][j]);
            wf[kb][j] = (short)f2bf(p);
        }
    }

    #pragma unroll
    for (int c = 0; c < 4; c++) {
        #pragma unroll
        for (int kb = 0; kb < 2; kb++) {
            int row = c * 16 + lr;
            int byteoff = (row * 128 + (kb * 32 + lg * 8) * 2) ^ ((row & 7) << 4);
            s16x8 bWc = *(const s16x8*)((const char*)&sWT[0][0] + byteoff);
            s16x8 bWe = *(const s16x8*)((const char*)&sWT[1][0] + byteoff);
            acc[c] = __builtin_amdgcn_mfma_f32_16x16x32_bf16(sf[kb], bWc, acc[c], 0, 0, 0);
            acc[c] = __builtin_amdgcn_mfma_f32_16x16x32_bf16(wf[kb], bWe, acc[c], 0, 0, 0);
        }
    }

    float o[4][4];
    float ssq[4] = {0.f, 0.f, 0.f, 0.f};
    #pragma unroll
    for (int c = 0; c < 4; c++) {
        #pragma unroll
        for (int r = 0; r < 4; r++) {
            float x = acc[c][r];
            float y = (x > 0.f) ? x : 0.2f * x;
            o[c][r] = y;
            ssq[r] += y * y;
        }
    }
    #pragma unroll
    for (int r = 0; r < 4; r++) {
        ssq[r] += __shfl_xor(ssq[r], 1);
        ssq[r] += __shfl_xor(ssq[r], 2);
        ssq[r] += __shfl_xor(ssq[r], 4);
        ssq[r] += __shfl_xor(ssq[r], 8);
    }
    #pragma unroll
    for (int r = 0; r < 4; r++) {
        int row = n0 + wid * 16 + lg * 4 + r;
        if (row < NN) {
            float sc = 1.0f / fmaxf(sqrtf(ssq[r]), 1e-12f);
            #pragma unroll
            for (int c = 0; c < 4; c++) {
                __builtin_nontemporal_store(o[c][r] * sc,
                                            &outN[(size_t)row * OS + c * 16 + lr]);
                ebf_out[(size_t)row * D + c * 16 + lr] = f2bf(o[c][r]);
            }
        }
    }
}

extern "C" void kernel_launch(void* const* d_in, const int* in_sizes, int n_in,
                              void* d_out, int out_size, void* d_ws, size_t ws_size,
                              hipStream_t stream) {
    const int*   rows = (const int*)d_in[0];
    const int*   cols = (const int*)d_in[1];
    const float* vals = (const float*)d_in[2];
    const float* ue   = (const float*)d_in[3];
    const float* ie   = (const float*)d_in[4];
    const float* Wc   = (const float*)d_in[5];
    const float* bc   = (const float*)d_in[6];
    const float* We   = (const float*)d_in[7];
    const float* be   = (const float*)d_in[8];
    float* out = (float*)d_out;

    // ws layout (~87 MB): double-buffered ebf + CSR + W images.
    // cnt/cur overlap eb1 (eb1 first written by layer 0, after scatter).
    unsigned short* eb0 = (unsigned short*)d_ws;            // NN*D bf16 (38.4MB)
    unsigned short* eb1 = eb0 + (size_t)NN * D;             // NN*D bf16 (38.4MB)
    int*   cnt    = (int*)eb1;                              // NN (build only)
    int*   cur    = cnt + NN;                               // NN (build only)
    int*   rowptr = (int*)(eb1 + (size_t)NN * D);           // NN+1
    int*   bsum   = rowptr + NN + 1;                        // 512
    long long* ecv = (long long*)(bsum + 512);              // NNZE (9.6MB)
    unsigned short* wbf = (unsigned short*)(ecv + NNZE);    // 6*4096 bf16 (48KB)

    const int NB_SCAN = (NN + 1023) / 1024;  // 293

    hipMemsetAsync(cnt, 0, (size_t)NN * sizeof(int), stream);
    k_prepw<<<6, 256, 0, stream>>>(Wc, We, wbf);
    // concat + hist fused (independent work co-scheduled)
    k_concat<<<(NN * 16 + 255) / 256, 256, 0, stream>>>(ue, ie, out, eb0, rows, cnt);
    k_scan1<<<NB_SCAN, 1024, 0, stream>>>(cnt, rowptr, bsum);
    k_scan2<<<1, 512, 0, stream>>>(bsum, NB_SCAN);
    k_scan3<<<NB_SCAN, 1024, 0, stream>>>(rowptr, bsum, cur);
    k_scatter<<<(NNZE + 255) / 256, 256, 0, stream>>>(rows, cols, vals, cur, ecv);

    const int GB_FUSED = (NN + 63) / 64;
    unsigned short* eb[2] = {eb0, eb1};
    for (int l = 0; l < 3; l++) {
        k_fused<<<GB_FUSED, 256, 0, stream>>>(
            rowptr, ecv, eb[l & 1], eb[(l + 1) & 1],
            wbf + l * 8192, bc + l * 64, be + l * 64, out + (l + 1) * 64);
    }
}